// Round 1
// baseline (180.191 us; speedup 1.0000x reference)
//
#include <hip/hip_runtime.h>

typedef __attribute__((ext_vector_type(8))) short short8;
typedef __attribute__((ext_vector_type(4))) float f32x4;
typedef unsigned short ushort_t;

#define D_MODEL 768
#define NHEAD 12
#define HD 64
#define BATCH 4
#define HWIDTH 32
#define HW 1024
#define TOK (BATCH*HW)
#define QKV_N (3*D_MODEL)
#define BH (BATCH*NHEAD)

__device__ __forceinline__ ushort_t f2bf(float f) {
    union { float f; unsigned u; } v; v.f = f;
    unsigned u = v.u;
    unsigned r = u + 0x7FFFu + ((u >> 16) & 1u);
    return (ushort_t)(r >> 16);
}
__device__ __forceinline__ float bf2f(ushort_t h) {
    union { unsigned u; float f; } v; v.u = ((unsigned)h) << 16;
    return v.f;
}
__device__ __forceinline__ int iabs(int x) { return x < 0 ? -x : x; }

// ---------------- RMSNorm: one wave per token ----------------
__global__ void rmsnorm_kernel(const float* __restrict__ x, const float* __restrict__ gamma,
                               ushort_t* __restrict__ xn) {
    int wave = threadIdx.x >> 6, lane = threadIdx.x & 63;
    int t = blockIdx.x * 4 + wave;
    const float* xr = x + (size_t)t * D_MODEL;
    float v[12]; float ss = 0.f;
    #pragma unroll
    for (int j = 0; j < 12; ++j) { v[j] = xr[lane + j*64]; ss += v[j]*v[j]; }
    #pragma unroll
    for (int m = 1; m < 64; m <<= 1) ss += __shfl_xor(ss, m, 64);
    float r = rsqrtf(ss * (1.f/768.f) + 1e-6f);
    ushort_t* o = xn + (size_t)t * D_MODEL;
    #pragma unroll
    for (int j = 0; j < 12; ++j) o[lane + j*64] = f2bf(v[j] * r * gamma[lane + j*64]);
}

// ---------------- f32 -> bf16 convert ----------------
__global__ void cvt_kernel(const float* __restrict__ in, ushort_t* __restrict__ out, int n) {
    int i = blockIdx.x * blockDim.x + threadIdx.x;
    if (i < n) out[i] = f2bf(in[i]);
}

// ---------------- axial RoPE sin/cos tables (1024 x 32) ----------------
__global__ void sincos_kernel(float* __restrict__ sint, float* __restrict__ cost) {
    int i = blockIdx.x * blockDim.x + threadIdx.x; // 32768
    int p = i >> 5, j = i & 31;
    int r = p >> 5, c = p & 31;
    int jj = j & 15;
    float freq = powf(10000.f, -(float)(2*jj) / 32.f);
    float pos = (j < 16) ? (float)r : (float)c;
    float th = pos * freq;
    sint[i] = sinf(th);
    cost[i] = cosf(th);
}

// ---------------- bf16 B^T GEMM: C[M,N] = A[M,K] * B[N,K]^T ----------------
// 128x128 tile, BK=32, 4 waves (2x2), global_load_lds staging (m97 structure)
template<typename OutT>
__global__ __launch_bounds__(256) void gemm_bt(const ushort_t* __restrict__ A,
                                               const ushort_t* __restrict__ B,
                                               OutT* __restrict__ C, int M, int N, int K) {
    __shared__ ushort_t As[128*32];
    __shared__ ushort_t Bs[128*32];
    int tn = blockIdx.x * 128, tm = blockIdx.y * 128;
    int w = threadIdx.x >> 6, lane = threadIdx.x & 63;
    int wr = w >> 1, wc = w & 1;
    int l15 = lane & 15, l4 = lane >> 4;
    f32x4 acc[4][4] = {};
    for (int k0 = 0; k0 < K; k0 += 32) {
        #pragma unroll
        for (int is = 0; is < 2; ++is) {
            int c = is*256 + w*64 + lane;
            int row = c >> 2, cc = c & 3;
            const ushort_t* ga = A + (size_t)(tm + row)*K + k0 + cc*8;
            __builtin_amdgcn_global_load_lds((const __attribute__((address_space(1))) void*)ga,
                (__attribute__((address_space(3))) void*)(As + (size_t)(is*256 + w*64)*8), 16, 0, 0);
            const ushort_t* gb = B + (size_t)(tn + row)*K + k0 + cc*8;
            __builtin_amdgcn_global_load_lds((const __attribute__((address_space(1))) void*)gb,
                (__attribute__((address_space(3))) void*)(Bs + (size_t)(is*256 + w*64)*8), 16, 0, 0);
        }
        __syncthreads();
        short8 af[4], bfr[4];
        #pragma unroll
        for (int i = 0; i < 4; ++i)
            af[i] = *(const short8*)&As[(size_t)(wr*64 + i*16 + l15)*32 + l4*8];
        #pragma unroll
        for (int i = 0; i < 4; ++i)
            bfr[i] = *(const short8*)&Bs[(size_t)(wc*64 + i*16 + l15)*32 + l4*8];
        #pragma unroll
        for (int mi = 0; mi < 4; ++mi)
            #pragma unroll
            for (int ni = 0; ni < 4; ++ni)
                acc[mi][ni] = __builtin_amdgcn_mfma_f32_16x16x32_bf16(af[mi], bfr[ni], acc[mi][ni], 0, 0, 0);
        __syncthreads();
    }
    #pragma unroll
    for (int mi = 0; mi < 4; ++mi) {
        #pragma unroll
        for (int ni = 0; ni < 4; ++ni) {
            #pragma unroll
            for (int r = 0; r < 4; ++r) {
                int row = tm + wr*64 + mi*16 + l4*4 + r;
                int col = tn + wc*64 + ni*16 + l15;
                float val = acc[mi][ni][r];
                if constexpr (sizeof(OutT) == 2) C[(size_t)row*N + col] = f2bf(val);
                else                             C[(size_t)row*N + col] = val;
            }
        }
    }
}

// ---------------- RoPE apply + per-head layout for Q, K ----------------
// Q,K out: (BH, HW, HD) bf16 row-major
__global__ void rope_kernel(const ushort_t* __restrict__ qkv, const float* __restrict__ sint,
                            const float* __restrict__ cost, ushort_t* __restrict__ Q,
                            ushort_t* __restrict__ Kt) {
    int i = blockIdx.x * blockDim.x + threadIdx.x; // 48*1024*32
    int d = i & 31; int p = (i >> 5) & 1023; int bh = i >> 15;
    int b = bh / NHEAD, h = bh % NHEAD;
    size_t t = (size_t)b * HW + p;
    const ushort_t* row = qkv + t * QKV_N;
    float s = sint[p*32 + d], c = cost[p*32 + d];
    float q0 = bf2f(row[h*64 + d]), q1 = bf2f(row[h*64 + d + 32]);
    float k0 = bf2f(row[768 + h*64 + d]), k1 = bf2f(row[768 + h*64 + d + 32]);
    size_t o = (size_t)bh * HW * HD + (size_t)p * HD + d;
    Q[o]      = f2bf(q0*c - q1*s);
    Q[o + 32] = f2bf(q1*c + q0*s);
    Kt[o]      = f2bf(k0*c - k1*s);
    Kt[o + 32] = f2bf(k1*c + k0*s);
}

// ---------------- V transpose: VT (BH, HD, HW) bf16 ----------------
__global__ void vt_kernel(const ushort_t* __restrict__ qkv, ushort_t* __restrict__ VT) {
    int i = blockIdx.x * blockDim.x + threadIdx.x; // 48*64*1024
    int p = i & 1023; int d = (i >> 10) & 63; int bh = i >> 16;
    int b = bh / NHEAD, h = bh % NHEAD;
    size_t t = (size_t)b * HW + p;
    VT[(size_t)bh * HD * HW + (size_t)d * HW + p] = qkv[t * QKV_N + 1536 + h*64 + d];
}

// ---------------- flash attention with 3x3-neighbor exclusion mask ----------------
// grid (16, 48); block 256 = 4 waves; wave handles 16 q-rows, kv tiles of 64
__global__ __launch_bounds__(256) void attn_kernel(const ushort_t* __restrict__ Q,
                                                   const ushort_t* __restrict__ Kt,
                                                   const ushort_t* __restrict__ VT,
                                                   ushort_t* __restrict__ Ao) {
    __shared__ ushort_t P[4][16][80]; // padded rows (160B) for aligned b128 reads
    int bh = blockIdx.y;
    int w = threadIdx.x >> 6, lane = threadIdx.x & 63;
    int l15 = lane & 15, l4 = lane >> 4;
    int qbase = blockIdx.x * 64 + w * 16;
    const ushort_t* Qh = Q + (size_t)bh * HW * HD;
    const ushort_t* Kh = Kt + (size_t)bh * HW * HD;
    const ushort_t* Vh = VT + (size_t)bh * HD * HW;
    short8 aq0 = *(const short8*)&Qh[(size_t)(qbase + l15)*64 + l4*8];
    short8 aq1 = *(const short8*)&Qh[(size_t)(qbase + l15)*64 + 32 + l4*8];
    float m[4], lsum[4];
    f32x4 oacc[4] = {};
    #pragma unroll
    for (int i = 0; i < 4; ++i) { m[i] = -1e30f; lsum[i] = 0.f; }
    int qq[4], qr[4], qc[4];
    #pragma unroll
    for (int i = 0; i < 4; ++i) { qq[i] = qbase + l4*4 + i; qr[i] = qq[i] >> 5; qc[i] = qq[i] & 31; }

    for (int kv = 0; kv < HW; kv += 64) {
        f32x4 s[4];
        #pragma unroll
        for (int st = 0; st < 4; ++st) {
            int kb = kv + st*16;
            short8 bk0 = *(const short8*)&Kh[(size_t)(kb + l15)*64 + l4*8];
            short8 bk1 = *(const short8*)&Kh[(size_t)(kb + l15)*64 + 32 + l4*8];
            f32x4 z = {};
            z = __builtin_amdgcn_mfma_f32_16x16x32_bf16(aq0, bk0, z, 0, 0, 0);
            z = __builtin_amdgcn_mfma_f32_16x16x32_bf16(aq1, bk1, z, 0, 0, 0);
            s[st] = z;
        }
        #pragma unroll
        for (int st = 0; st < 4; ++st) {
            int kq = kv + st*16 + l15;
            int kr = kq >> 5, kc = kq & 31;
            #pragma unroll
            for (int i = 0; i < 4; ++i) {
                bool excl = (iabs(qr[i]-kr) <= 1) && (iabs(qc[i]-kc) <= 1);
                float val = s[st][i] * 0.125f;
                s[st][i] = excl ? -1e30f : val;
            }
        }
        #pragma unroll
        for (int i = 0; i < 4; ++i) {
            float vmax = fmaxf(fmaxf(s[0][i], s[1][i]), fmaxf(s[2][i], s[3][i]));
            #pragma unroll
            for (int msk = 1; msk < 16; msk <<= 1) vmax = fmaxf(vmax, __shfl_xor(vmax, msk, 64));
            float mn = fmaxf(m[i], vmax);
            float sf = __expf(m[i] - mn);
            m[i] = mn;
            lsum[i] *= sf;
            #pragma unroll
            for (int dt = 0; dt < 4; ++dt) oacc[dt][i] *= sf;
            float ls = 0.f;
            #pragma unroll
            for (int st = 0; st < 4; ++st) {
                float p = __expf(s[st][i] - mn);
                s[st][i] = p;
                ls += p;
            }
            #pragma unroll
            for (int msk = 1; msk < 16; msk <<= 1) ls += __shfl_xor(ls, msk, 64);
            lsum[i] += ls;
        }
        #pragma unroll
        for (int st = 0; st < 4; ++st)
            #pragma unroll
            for (int i = 0; i < 4; ++i)
                P[w][l4*4 + i][st*16 + l15] = f2bf(s[st][i]);
        short8 pa0 = *(const short8*)&P[w][l15][l4*8];
        short8 pa1 = *(const short8*)&P[w][l15][32 + l4*8];
        #pragma unroll
        for (int dt = 0; dt < 4; ++dt) {
            short8 bv0 = *(const short8*)&Vh[(size_t)(dt*16 + l15)*HW + kv + l4*8];
            short8 bv1 = *(const short8*)&Vh[(size_t)(dt*16 + l15)*HW + kv + 32 + l4*8];
            oacc[dt] = __builtin_amdgcn_mfma_f32_16x16x32_bf16(pa0, bv0, oacc[dt], 0, 0, 0);
            oacc[dt] = __builtin_amdgcn_mfma_f32_16x16x32_bf16(pa1, bv1, oacc[dt], 0, 0, 0);
        }
    }
    int b = bh / NHEAD, h = bh % NHEAD;
    #pragma unroll
    for (int dt = 0; dt < 4; ++dt) {
        #pragma unroll
        for (int i = 0; i < 4; ++i) {
            int t = b*HW + qq[i];
            Ao[(size_t)t*D_MODEL + h*64 + dt*16 + l15] = f2bf(oacc[dt][i] / lsum[i]);
        }
    }
}

extern "C" void kernel_launch(void* const* d_in, const int* in_sizes, int n_in,
                              void* d_out, int out_size, void* d_ws, size_t ws_size,
                              hipStream_t stream) {
    const float* x      = (const float*)d_in[0];
    const float* w_qkv  = (const float*)d_in[1];
    const float* w_out  = (const float*)d_in[2];
    const float* gamma  = (const float*)d_in[3];
    float* out = (float*)d_out;

    char* ws = (char*)d_ws;
    size_t off = 0;
    auto alloc = [&](size_t bytes) { char* p = ws + off; off += (bytes + 255) & ~255ull; return p; };
    ushort_t* xn   = (ushort_t*)alloc((size_t)TOK*D_MODEL*2);
    ushort_t* wq   = (ushort_t*)alloc((size_t)QKV_N*D_MODEL*2);
    ushort_t* wo   = (ushort_t*)alloc((size_t)D_MODEL*D_MODEL*2);
    float* sint    = (float*)alloc((size_t)HW*32*4);
    float* cost    = (float*)alloc((size_t)HW*32*4);
    ushort_t* qkv  = (ushort_t*)alloc((size_t)TOK*QKV_N*2);
    ushort_t* Qr   = (ushort_t*)alloc((size_t)BH*HW*HD*2);
    ushort_t* Kr   = (ushort_t*)alloc((size_t)BH*HW*HD*2);
    ushort_t* VTt  = (ushort_t*)alloc((size_t)BH*HD*HW*2);
    ushort_t* Ao   = (ushort_t*)alloc((size_t)TOK*D_MODEL*2);

    rmsnorm_kernel<<<TOK/4, 256, 0, stream>>>(x, gamma, xn);
    cvt_kernel<<<(QKV_N*D_MODEL + 255)/256, 256, 0, stream>>>(w_qkv, wq, QKV_N*D_MODEL);
    cvt_kernel<<<(D_MODEL*D_MODEL + 255)/256, 256, 0, stream>>>(w_out, wo, D_MODEL*D_MODEL);
    sincos_kernel<<<HW*32/256, 256, 0, stream>>>(sint, cost);
    gemm_bt<ushort_t><<<dim3(QKV_N/128, TOK/128), 256, 0, stream>>>(xn, wq, qkv, TOK, QKV_N, D_MODEL);
    rope_kernel<<<BH*HW*32/256, 256, 0, stream>>>(qkv, sint, cost, Qr, Kr);
    vt_kernel<<<BH*HD*HW/256, 256, 0, stream>>>(qkv, VTt);
    attn_kernel<<<dim3(HW/64, BH), 256, 0, stream>>>(Qr, Kr, VTt, Ao);
    gemm_bt<float><<<dim3(D_MODEL/128, TOK/128), 256, 0, stream>>>(Ao, wo, out, TOK, D_MODEL, D_MODEL);
}